// Round 7
// baseline (84.010 us; speedup 1.0000x reference)
//
#include <hip/hip_runtime.h>

// SO3 encode: z[B, 96] -> (mean[B,16,3,3], logvar[B,16,3]) concatenated flat.
// mean = I + s1*A + s2*A^2 (Rodrigues), logvar = 5.4*sigmoid(logits) - 9.2
//
// R7: output-driven, zero LDS. One thread per OUTPUT float4.
//  - q < M4 (mean region): f4 covers mean floats 4q..4q+3 -> Rodrigues of
//    gaussian g0=4q/9 and g0+1 (both computed into named registers, static
//    indexing only), 9-case switch selects the 4 floats. Adjacent lanes'
//    axis loads overlap -> same cache lines, HBM reads unchanged.
//  - q >= M4 (logvar region): pure elementwise f4 map (aligned both sides).
// Boundary is block-exact (M4 % 256 == 0) -> the range branch is
// block-uniform. Pure load->compute->store streaming like the fill kernel.

#define BLOCK 256

typedef float f4 __attribute__((ext_vector_type(4)));

struct M9 { float e0, e1, e2, e3, e4, e5, e6, e7, e8; };

__device__ __forceinline__ M9 rodrigues(float a, float b, float c) {
    float th2 = a * a + b * b + c * c;
    bool small = th2 < 1e-8f;
    float t2 = small ? 1.0f : th2;        // safe denom, matches reference
    float t = sqrtf(t2);
    float sn, cs;
    __sincosf(t, &sn, &cs);
    float inv = 1.0f / t2;
    float s1 = small ? (1.0f - th2 * (1.0f / 6.0f))  : (sn * t * inv);      // sin(t)/t
    float s2 = small ? (0.5f - th2 * (1.0f / 24.0f)) : ((1.0f - cs) * inv); // (1-cos t)/t^2
    float ab = a * b, ac = a * c, bc = b * c;
    M9 m;
    m.e0 = 1.0f - s2 * (a * a + b * b);
    m.e1 = s1 * a - s2 * bc;
    m.e2 = s1 * b + s2 * ac;
    m.e3 = -s1 * a - s2 * bc;
    m.e4 = 1.0f - s2 * (a * a + c * c);
    m.e5 = s1 * c - s2 * ab;
    m.e6 = -s1 * b + s2 * ac;
    m.e7 = -s1 * c - s2 * ab;
    m.e8 = 1.0f - s2 * (b * b + c * c);
    return m;
}

__global__ __launch_bounds__(BLOCK, 8) void so3_encode_kernel(
    const float* __restrict__ z,
    float* __restrict__ out,        // mean region then logvar region, flat
    unsigned M4,                    // f4 count of mean region = B*36
    unsigned NG)                    // total gaussians = B*16
{
    const unsigned q = blockIdx.x * BLOCK + threadIdx.x;   // grid exact
    f4* outv = reinterpret_cast<f4*>(out);

    if (q < M4) {
        // ---- mean: out floats 4q..4q+3
        unsigned j0 = 4u * q;
        unsigned g0 = j0 / 9u;                 // compiler magic-mul
        unsigned r  = j0 - 9u * g0;            // 0..8
        unsigned g1 = g0 + 1u;
        if (g1 >= NG) g1 = NG - 1u;            // clamp (unused when clamped)

        unsigned a0 = (g0 >> 4) * 96u + (g0 & 15u) * 3u;
        unsigned a1 = (g1 >> 4) * 96u + (g1 & 15u) * 3u;
        const float* p0 = z + a0;
        const float* p1 = z + a1;
        M9 m0 = rodrigues(p0[0], p0[1], p0[2]);
        M9 m1 = rodrigues(p1[0], p1[1], p1[2]);

        f4 o;
        switch (r) {
            case 0: o.x = m0.e0; o.y = m0.e1; o.z = m0.e2; o.w = m0.e3; break;
            case 1: o.x = m0.e1; o.y = m0.e2; o.z = m0.e3; o.w = m0.e4; break;
            case 2: o.x = m0.e2; o.y = m0.e3; o.z = m0.e4; o.w = m0.e5; break;
            case 3: o.x = m0.e3; o.y = m0.e4; o.z = m0.e5; o.w = m0.e6; break;
            case 4: o.x = m0.e4; o.y = m0.e5; o.z = m0.e6; o.w = m0.e7; break;
            case 5: o.x = m0.e5; o.y = m0.e6; o.z = m0.e7; o.w = m0.e8; break;
            case 6: o.x = m0.e6; o.y = m0.e7; o.z = m0.e8; o.w = m1.e0; break;
            case 7: o.x = m0.e7; o.y = m0.e8; o.z = m1.e0; o.w = m1.e1; break;
            default: o.x = m0.e8; o.y = m1.e0; o.z = m1.e1; o.w = m1.e2; break;
        }
        outv[q] = o;
    } else {
        // ---- logvar: elementwise f4 map (both sides 16B aligned)
        unsigned u   = q - M4;
        unsigned row = u / 12u;                // compiler magic-mul
        unsigned col = u - 12u * row;
        const f4* src = reinterpret_cast<const f4*>(z + (size_t)row * 96 + 48) + col;
        f4 v = *src;
        f4 o;
        o.x = 5.4f / (1.0f + __expf(-v.x)) - 9.2f;
        o.y = 5.4f / (1.0f + __expf(-v.y)) - 9.2f;
        o.z = 5.4f / (1.0f + __expf(-v.z)) - 9.2f;
        o.w = 5.4f / (1.0f + __expf(-v.w)) - 9.2f;
        outv[q] = o;
    }
}

extern "C" void kernel_launch(void* const* d_in, const int* in_sizes, int n_in,
                              void* d_out, int out_size, void* d_ws, size_t ws_size,
                              hipStream_t stream) {
    const float* z = (const float*)d_in[0];
    const int B = in_sizes[0] / 96;            // 6 * N_GAUSS = 96 floats per row
    const unsigned M4 = (unsigned)B * 36u;     // mean f4s  (B*144 floats / 4)
    const unsigned L4 = (unsigned)B * 12u;     // logvar f4s (B*48 floats / 4)
    const unsigned NG = (unsigned)B * 16u;

    const unsigned total = M4 + L4;            // 12,582,912 -> 49152 blocks exact
    const unsigned grid = (total + BLOCK - 1) / BLOCK;
    so3_encode_kernel<<<grid, BLOCK, 0, stream>>>(z, (float*)d_out, M4, NG);
}

// Round 8
// 57.369 us; speedup vs baseline: 1.4644x; 1.4644x over previous
//
#include <hip/hip_runtime.h>

// SO3 encode: z[B, 96] -> (mean[B,16,3,3], logvar[B,16,3]) concatenated flat.
// mean = I + s1*A + s2*A^2 (Rodrigues), logvar = 5.4*sigmoid(logits) - 9.2
//
// R8: two block-uniform grid regions in one kernel.
//  - Mean blocks (R6's winning path, trimmed): one gaussian per thread,
//    3 scalar axis loads, Rodrigues, stage 9 floats to wave-private LDS,
//    same-wave lgkmcnt fence (no s_barrier), coalesced f4 readout.
//    LDS now 9 KB/block (logvar staging removed) -> 8 blocks/CU.
//  - Logvar blocks: pure elementwise f4 map, both sides 16B-aligned,
//    zero LDS, fill-kernel-like streaming.
// R7 post-mortem: output-driven/no-LDS regressed (2x Rodrigues + scalar
// gathers + divergent select -> issue-bound). LDS transpose stays.

#define BLOCK 256

typedef float f4 __attribute__((ext_vector_type(4)));

__global__ __launch_bounds__(BLOCK, 8) void so3_encode_kernel(
    const float* __restrict__ z,
    float* __restrict__ out_mean,
    float* __restrict__ out_logvar,
    unsigned nb_mean)               // #blocks in the mean region
{
    __shared__ float smean[4][64 * 9];   // per-wave 2304 B, total 9 KB

    if (blockIdx.x < nb_mean) {
        // ================= mean region =================
        const int t    = threadIdx.x;
        const int lane = t & 63;
        const int w    = t >> 6;
        const int g    = blockIdx.x * BLOCK + t;   // gaussian index (exact grid)
        const int b    = g >> 4;                   // batch row
        const int s    = g & 15;                   // slot in row

        const float* zr = z + (size_t)b * 96 + s * 3;
        float a  = zr[0];
        float bb = zr[1];
        float c  = zr[2];

        float th2 = a * a + bb * bb + c * c;
        bool small = th2 < 1e-8f;
        float t2 = small ? 1.0f : th2;        // safe denom, matches reference
        float tt = sqrtf(t2);
        float sn, cs;
        __sincosf(tt, &sn, &cs);
        float inv_t2 = 1.0f / t2;
        float s1 = small ? (1.0f - th2 * (1.0f / 6.0f))  : (sn * tt * inv_t2);
        float s2 = small ? (0.5f - th2 * (1.0f / 24.0f)) : ((1.0f - cs) * inv_t2);

        float ab = a * bb, ac = a * c, bc = bb * c;
        float* sm = &smean[w][lane * 9];       // stride 9: gcd(9,32)=1, conflict-free
        sm[0] = 1.0f - s2 * (a * a + bb * bb);
        sm[1] = s1 * a  - s2 * bc;
        sm[2] = s1 * bb + s2 * ac;
        sm[3] = -s1 * a - s2 * bc;
        sm[4] = 1.0f - s2 * (a * a + c * c);
        sm[5] = s1 * c  - s2 * ab;
        sm[6] = -s1 * bb + s2 * ac;
        sm[7] = -s1 * c  - s2 * ab;
        sm[8] = 1.0f - s2 * (bb * bb + c * c);

        // same-wave write->read fence (exchange is wave-local only)
        asm volatile("s_waitcnt lgkmcnt(0)" ::: "memory");
        __builtin_amdgcn_sched_barrier(0);

        // coalesced readout: 144 f4 per wave, contiguous
        const int g_base = blockIdx.x * BLOCK + (w << 6);
        const f4* smv = reinterpret_cast<const f4*>(&smean[w][0]);
        f4* om = reinterpret_cast<f4*>(out_mean + (size_t)g_base * 9);
        om[lane]      = smv[lane];
        om[64 + lane] = smv[64 + lane];
        if (lane < 16) om[128 + lane] = smv[128 + lane];
    } else {
        // ================= logvar region: elementwise f4 =================
        const unsigned u = (blockIdx.x - nb_mean) * BLOCK + threadIdx.x; // f4 index
        unsigned row = u / 12u;                // compiler magic-mul
        unsigned col = u - 12u * row;
        const f4* src = reinterpret_cast<const f4*>(z + (size_t)row * 96 + 48) + col;
        f4 v = *src;
        f4 o;
        o.x = 5.4f / (1.0f + __expf(-v.x)) - 9.2f;
        o.y = 5.4f / (1.0f + __expf(-v.y)) - 9.2f;
        o.z = 5.4f / (1.0f + __expf(-v.z)) - 9.2f;
        o.w = 5.4f / (1.0f + __expf(-v.w)) - 9.2f;
        reinterpret_cast<f4*>(out_logvar)[u] = o;
    }
}

extern "C" void kernel_launch(void* const* d_in, const int* in_sizes, int n_in,
                              void* d_out, int out_size, void* d_ws, size_t ws_size,
                              hipStream_t stream) {
    const float* z = (const float*)d_in[0];
    const int B = in_sizes[0] / 96;            // 6 * N_GAUSS = 96 floats per row
    float* out_mean = (float*)d_out;                              // B*144 floats
    float* out_logvar = (float*)d_out + (size_t)B * 144;          // B*48 floats

    const unsigned nb_mean = (unsigned)B * 16u / BLOCK;   // 16384 (exact)
    const unsigned nb_lv   = (unsigned)B * 12u / BLOCK;   // 12288 (exact: B*48/4 f4)
    so3_encode_kernel<<<nb_mean + nb_lv, BLOCK, 0, stream>>>(
        z, out_mean, out_logvar, nb_mean);
}

// Round 9
// 52.468 us; speedup vs baseline: 1.6012x; 1.0934x over previous
//
#include <hip/hip_runtime.h>

// SO3 encode: z[B, 96] -> (mean[B,16,3,3], logvar[B,16,3]) concatenated flat.
// mean = I + s1*A + s2*A^2 (Rodrigues), logvar = 5.4*sigmoid(logits) - 9.2
//
// R9 = R6 structure + direct (no-LDS) logvar within the same block.
// Block owns 16 complete z rows (256 gaussians): full 384-B rows are
// consumed by one block -> every cache line fetched once (R8 post-mortem:
// splitting mean/logvar into separate grid phases refetched the middle
// 128-B line of each row, +11%).
//  - mean: one gaussian/thread, 3 scalar axis loads, Rodrigues, stage 9
//    floats to wave-private LDS (stride 9, gcd(9,32)=1 conflict-free),
//    same-wave lgkmcnt fence (no s_barrier), coalesced f4 readout.
//  - logvar: threads 0..191 map the block's 192 logvar f4s elementwise
//    (aligned f4 load -> 4 sigmoids -> aligned f4 store), no LDS, issued
//    before the fence. Waves 0-2 fully active, wave 3 skips (wave-uniform).

#define BLOCK 256

typedef float f4 __attribute__((ext_vector_type(4)));

__global__ __launch_bounds__(BLOCK, 8) void so3_encode_kernel(
    const float* __restrict__ z,
    float* __restrict__ out_mean,
    float* __restrict__ out_logvar)
{
    __shared__ float smean[4][64 * 9];   // per-wave 2304 B, total 9 KB

    const int t    = threadIdx.x;
    const int lane = t & 63;
    const int w    = t >> 6;
    const int g    = blockIdx.x * BLOCK + t;   // gaussian index (grid exact)
    const int b    = g >> 4;                   // batch row
    const int s    = g & 15;                   // slot in row

    // ---- logvar load first (overlaps Rodrigues latency)
    f4 lvv;
    unsigned u = 0;
    if (t < 192) {
        u = (unsigned)blockIdx.x * 192u + t;   // f4 index into out_logvar
        unsigned row = u / 12u;                // = blockIdx*16 + t/12
        unsigned col = u - 12u * row;
        lvv = *(reinterpret_cast<const f4*>(z + (size_t)row * 96 + 48) + col);
    }

    // ---- mean path: 3 scalar axis loads + Rodrigues
    const float* zr = z + (size_t)b * 96 + s * 3;
    float a  = zr[0];
    float bb = zr[1];
    float c  = zr[2];

    float th2 = a * a + bb * bb + c * c;
    bool small = th2 < 1e-8f;
    float t2 = small ? 1.0f : th2;        // safe denom, matches reference
    float tt = sqrtf(t2);
    float sn, cs;
    __sincosf(tt, &sn, &cs);
    float inv_t2 = 1.0f / t2;
    float s1 = small ? (1.0f - th2 * (1.0f / 6.0f))  : (sn * tt * inv_t2);
    float s2 = small ? (0.5f - th2 * (1.0f / 24.0f)) : ((1.0f - cs) * inv_t2);

    float ab = a * bb, ac = a * c, bc = bb * c;
    float* sm = &smean[w][lane * 9];       // stride 9: conflict-free
    sm[0] = 1.0f - s2 * (a * a + bb * bb);
    sm[1] = s1 * a  - s2 * bc;
    sm[2] = s1 * bb + s2 * ac;
    sm[3] = -s1 * a - s2 * bc;
    sm[4] = 1.0f - s2 * (a * a + c * c);
    sm[5] = s1 * c  - s2 * ab;
    sm[6] = -s1 * bb + s2 * ac;
    sm[7] = -s1 * c  - s2 * ab;
    sm[8] = 1.0f - s2 * (bb * bb + c * c);

    // ---- logvar compute+store (independent of LDS, before the fence)
    if (t < 192) {
        f4 o;
        o.x = 5.4f / (1.0f + __expf(-lvv.x)) - 9.2f;
        o.y = 5.4f / (1.0f + __expf(-lvv.y)) - 9.2f;
        o.z = 5.4f / (1.0f + __expf(-lvv.z)) - 9.2f;
        o.w = 5.4f / (1.0f + __expf(-lvv.w)) - 9.2f;
        reinterpret_cast<f4*>(out_logvar)[u] = o;
    }

    // ---- same-wave write->read fence (LDS exchange is wave-local only)
    asm volatile("s_waitcnt lgkmcnt(0)" ::: "memory");
    __builtin_amdgcn_sched_barrier(0);

    // ---- coalesced mean readout: 144 f4 per wave, contiguous
    const int g_base = blockIdx.x * BLOCK + (w << 6);
    const f4* smv = reinterpret_cast<const f4*>(&smean[w][0]);
    f4* om = reinterpret_cast<f4*>(out_mean + (size_t)g_base * 9);
    om[lane]      = smv[lane];
    om[64 + lane] = smv[64 + lane];
    if (lane < 16) om[128 + lane] = smv[128 + lane];
}

extern "C" void kernel_launch(void* const* d_in, const int* in_sizes, int n_in,
                              void* d_out, int out_size, void* d_ws, size_t ws_size,
                              hipStream_t stream) {
    const float* z = (const float*)d_in[0];
    const int B = in_sizes[0] / 96;            // 6 * N_GAUSS = 96 floats per row
    float* out_mean = (float*)d_out;                              // B*144 floats
    float* out_logvar = (float*)d_out + (size_t)B * 144;          // B*48 floats

    const int grid = B * 16 / BLOCK;           // 16384 blocks (exact)
    so3_encode_kernel<<<grid, BLOCK, 0, stream>>>(z, out_mean, out_logvar);
}

// Round 10
// 51.568 us; speedup vs baseline: 1.6291x; 1.0174x over previous
//
#include <hip/hip_runtime.h>

// SO3 encode: z[B, 96] -> (mean[B,16,3,3], logvar[B,16,3])
// mean = I + s1*A + s2*A^2 (Rodrigues), logvar = 5.4*sigmoid(logits) - 9.2
//
// FINAL (= R6, the session best: 51.66us, 5.85 TB/s end-to-end, ~97% of the
// 6.29 TB/s copy-ubench steady-state after launch overhead).
// One gaussian per thread; 12 KB LDS/block -> 32 waves/CU occupancy cap.
//   - input: consecutive lanes own consecutive 12-B chunks -> coalesced
//   - LDS mean writes: stride 9 floats, gcd(9,32)=1 -> conflict-free
//   - LDS logvar writes: stride 3, gcd(3,32)=1 -> conflict-free
//   - readout: linear float4, contiguous 1 KB per wave-store instruction
//   - all exchange wave-local -> s_waitcnt lgkmcnt(0), no s_barrier
// Session post-mortems: NT hints -22% (defeat L2 write aggregation);
// no-LDS output-driven -63% (issue-bound); split mean/logvar grid -11%
// (row locality loss); block s_barrier vs wave fence: free.

#define BLOCK 256

typedef float f4 __attribute__((ext_vector_type(4)));

__global__ __launch_bounds__(BLOCK, 8) void so3_encode_kernel(
    const float* __restrict__ z,
    float* __restrict__ out_mean,
    float* __restrict__ out_logvar)
{
    __shared__ float smean[4][64 * 9];   // per-wave 2304 B, total 9 KB
    __shared__ float slv[4][64 * 3];     // per-wave  768 B, total 3 KB

    const int t    = threadIdx.x;
    const int lane = t & 63;
    const int w    = t >> 6;
    const int g    = blockIdx.x * BLOCK + t;   // gaussian index, grid exact
    const int b    = g >> 4;                   // batch row
    const int s    = g & 15;                   // gaussian slot in row

    // axis params z[b, s*3 .. s*3+2], logits z[b, 48 + s*3 .. ]
    const float* zr = z + (size_t)b * 96 + s * 3;
    float a  = zr[0];
    float bb = zr[1];
    float c  = zr[2];
    float x0 = zr[48];
    float x1 = zr[49];
    float x2 = zr[50];

    // ---- Rodrigues
    float th2 = a * a + bb * bb + c * c;
    bool small = th2 < 1e-8f;
    float t2 = small ? 1.0f : th2;        // safe denom, matches reference
    float tt = sqrtf(t2);
    float sn, cs;
    __sincosf(tt, &sn, &cs);
    float inv_t2 = 1.0f / t2;
    float s1 = small ? (1.0f - th2 * (1.0f / 6.0f))  : (sn * tt * inv_t2);     // sin(t)/t
    float s2 = small ? (0.5f - th2 * (1.0f / 24.0f)) : ((1.0f - cs) * inv_t2); // (1-cos t)/t^2

    float ab = a * bb, ac = a * c, bc = bb * c;
    float* sm = &smean[w][lane * 9];
    sm[0] = 1.0f - s2 * (a * a + bb * bb);
    sm[1] = s1 * a  - s2 * bc;
    sm[2] = s1 * bb + s2 * ac;
    sm[3] = -s1 * a - s2 * bc;
    sm[4] = 1.0f - s2 * (a * a + c * c);
    sm[5] = s1 * c  - s2 * ab;
    sm[6] = -s1 * bb + s2 * ac;
    sm[7] = -s1 * c  - s2 * ab;
    sm[8] = 1.0f - s2 * (bb * bb + c * c);

    float* sl = &slv[w][lane * 3];
    sl[0] = 5.4f / (1.0f + __expf(-x0)) - 9.2f;
    sl[1] = 5.4f / (1.0f + __expf(-x1)) - 9.2f;
    sl[2] = 5.4f / (1.0f + __expf(-x2)) - 9.2f;

    // ---- same-wave write->read fence (exchange is wave-local only)
    asm volatile("s_waitcnt lgkmcnt(0)" ::: "memory");
    __builtin_amdgcn_sched_barrier(0);

    // ---- coalesced writeout
    const int g_base = blockIdx.x * BLOCK + (w << 6);

    const f4* smv = reinterpret_cast<const f4*>(&smean[w][0]);   // 144 f4
    f4* om = reinterpret_cast<f4*>(out_mean + (size_t)g_base * 9);
    om[lane]      = smv[lane];
    om[64 + lane] = smv[64 + lane];
    if (lane < 16) om[128 + lane] = smv[128 + lane];

    const f4* slvv = reinterpret_cast<const f4*>(&slv[w][0]);    // 48 f4
    f4* ol = reinterpret_cast<f4*>(out_logvar + (size_t)g_base * 3);
    if (lane < 48) ol[lane] = slvv[lane];
}

extern "C" void kernel_launch(void* const* d_in, const int* in_sizes, int n_in,
                              void* d_out, int out_size, void* d_ws, size_t ws_size,
                              hipStream_t stream) {
    const float* z = (const float*)d_in[0];
    const int B = in_sizes[0] / 96;          // 6 * N_GAUSS = 96 floats per row
    float* out_mean = (float*)d_out;                              // B*16*9 floats
    float* out_logvar = (float*)d_out + (size_t)B * 16 * 9;       // B*16*3 floats

    const int nthreads = B * 16;             // one thread per gaussian
    const int grid = nthreads / BLOCK;       // 4,194,304 / 256 = 16384 blocks
    so3_encode_kernel<<<grid, BLOCK, 0, stream>>>(z, out_mean, out_logvar);
}